// Round 8
// baseline (118.636 us; speedup 1.0000x reference)
//
#include <hip/hip_runtime.h>
#include <hip/hip_bf16.h>
#include <hip/hip_fp8.h>
#include <math.h>

typedef float f32x4 __attribute__((ext_vector_type(4)));
typedef int   i32x4 __attribute__((ext_vector_type(4)));
typedef int   v8i   __attribute__((ext_vector_type(8)));

constexpr int Nn = 8192;   // B*S
constexpr int Dd = 256;    // feature dim (== bytes per fp8 row)
constexpr float LOG2E     = 1.4426950408889634f;
constexpr float SIM_SCALE = 20.0f * LOG2E;   // (1/tau)*log2(e), tau=0.05
constexpr float SIM_BIAS  = -20.0f * LOG2E;  // fixed max = 1/tau (|q.k|<=1)
constexpr int   SCALE1    = 0x7F7F7F7F;      // E8M0 127 = 2^0 in every byte

// ---------------------------------------------------------------------------
// Kernel 1: L2-normalize rows -> fp8 e4m3; init cbias (SIM_BIAS pre-folded) /
// g_all / g_pos.  (Correctness-verified, unchanged.)
// ---------------------------------------------------------------------------
__global__ __launch_bounds__(256) void prep_kernel(const float* __restrict__ logits,
                                                   const float* __restrict__ labels,
                                                   const int* __restrict__ pad,
                                                   unsigned char* __restrict__ qb,
                                                   unsigned char* __restrict__ kb,
                                                   float* __restrict__ cbias,
                                                   float* __restrict__ g_all,
                                                   float* __restrict__ g_pos) {
  const int j = blockIdx.x * 256 + threadIdx.x;
  if (j < Nn) {
    cbias[j] = pad[j] ? SIM_BIAS : -1e30f;   // SIM_BIAS folded in (col term)
    g_all[j] = 0.0f;
    g_pos[j] = 0.0f;
  }

  const int gw   = (blockIdx.x * 256 + threadIdx.x) >> 6;
  const int lane = threadIdx.x & 63;
  const float* src;
  unsigned char* dst;
  int row;
  if (gw < Nn) { src = logits; dst = qb; row = gw; }
  else         { src = labels; dst = kb; row = gw - Nn; }

  const float4 v = *reinterpret_cast<const float4*>(src + (size_t)row * Dd + lane * 4);
  float ss = v.x * v.x + v.y * v.y + v.z * v.z + v.w * v.w;
#pragma unroll
  for (int m = 32; m >= 1; m >>= 1) ss += __shfl_xor(ss, m);
  const float scale = 1.0f / fmaxf(sqrtf(ss), 1e-12f);

  const __hip_fp8_e4m3 e0(v.x * scale);
  const __hip_fp8_e4m3 e1(v.y * scale);
  const __hip_fp8_e4m3 e2(v.z * scale);
  const __hip_fp8_e4m3 e3(v.w * scale);
  const unsigned int packed = (unsigned int)e0.__x |
                              ((unsigned int)e1.__x << 8) |
                              ((unsigned int)e2.__x << 16) |
                              ((unsigned int)e3.__x << 24);
  reinterpret_cast<unsigned int*>(dst + (size_t)row * Dd)[lane] = packed;
}

// ---------------------------------------------------------------------------
// Kernel 2 (R21): BARRIER-FREE / LDS-FREE.  Diagnosis across R16-R20: gemm is
// pinned at ~32-35us under every staged schedule (ILP, bytes, counted-vmcnt,
// occupancy all null) -> the stage->barrier->consume skeleton IS the cost
// (m233: ~70% of a 2-phase loop's critical path).  B is 2MiB fp8 = L2-resident,
// and each lane's MFMA operand is 32 CONTIGUOUS K-bytes at col*256+kk*128+qd*32
// -> load fragments straight from global with plain 16B loads:
//   - A fragments hoisted to regs once (16 x dwordx4 from qb).
//   - Per col-tile: 16 B-loads + 32 MFMA + exp2 epilogue.  NO __syncthreads,
//     NO LDS, NO DMA, NO bank conflicts; compiler emits precise per-register
//     vmcnt counts for plain loads; waves free-run (epilogue of one overlaps
//     MFMA of others without barrier coupling).
//   - A wave's 64 lanes (16 cols x qd*32 + {0,16}) tile every touched 64B
//     line -> zero over-fetch; L2 traffic ~295MB ≈ 8.5us at 34.5TB/s.
// Fragment math / C-layout / epilogue formula byte-identical to the verified
// R13..R19 path (operands are the same bytes, sourced from L2 not LDS).
// Block 128 rows x 1024 cols, grid (64,8), 256thr; regs ~215 under (256,2).
// ---------------------------------------------------------------------------
__global__ __launch_bounds__(256, 2) void gemm_lse_kernel(const unsigned char* __restrict__ qb,
                                                          const unsigned char* __restrict__ kb,
                                                          const float* __restrict__ cbias,
                                                          const int* __restrict__ ad,
                                                          float* __restrict__ g_all,
                                                          float* __restrict__ g_pos) {
  const int tid  = threadIdx.x;
  const int lane = tid & 63;
  const int w    = tid >> 6;        // 0..3
  const int wrow  = (w >> 1) * 64;  // 0 or 64
  const int wcolL = (w & 1) * 64;   // 0 or 64 within the 128-col tile
  const int lq   = lane & 15;
  const int qd   = lane >> 4;
  const int rowBase = blockIdx.x * 128;
  const int colBase = blockIdx.y * 1024;   // 8 col-tiles of 128

  // ---- A fragments straight from global (once; qb is L2-resident) ----
  // lane (lq,qd), tile mt, half kk: 32 K-bytes at row (wrow+mt*16+lq),
  // byte offset kk*128 + qd*32 (+0 / +16).
  const unsigned char* pA = qb + (size_t)(rowBase + wrow + lq) * Dd + qd * 32;
  v8i afReg[2][4];
#pragma unroll
  for (int kk = 0; kk < 2; ++kk)
#pragma unroll
    for (int mt = 0; mt < 4; ++mt) {
      const unsigned char* a = pA + mt * 16 * Dd + kk * 128;
      i32x4* ph_ = reinterpret_cast<i32x4*>(&afReg[kk][mt]);
      ph_[0] = *reinterpret_cast<const i32x4*>(a);
      ph_[1] = *reinterpret_cast<const i32x4*>(a + 16);
    }

  // per-thread row metadata + accumulators
  int rowAd[4][4];
#pragma unroll
  for (int mt = 0; mt < 4; ++mt)
#pragma unroll
    for (int r = 0; r < 4; ++r)
      rowAd[mt][r] = ad[rowBase + wrow + mt * 16 + qd * 4 + r];

  float apA[4][4], apP[4][4];
#pragma unroll
  for (int mt = 0; mt < 4; ++mt)
#pragma unroll
    for (int r = 0; r < 4; ++r) {
      apA[mt][r] = 0.f;
      apP[mt][r] = 0.f;
    }

  const unsigned char* pB = kb + (size_t)(colBase + wcolL + lq) * Dd + qd * 32;
  const float* pCb = cbias + colBase + wcolL + lq;
  const int*   pAd = ad    + colBase + wcolL + lq;
  const f32x4 CZ = (f32x4){0.f, 0.f, 0.f, 0.f};

  for (int ct = 0; ct < 8; ++ct) {
    const int cOff = ct * 128;  // column offset of this tile

    float colB[4];
    int colAd[4];
#pragma unroll
    for (int nt = 0; nt < 4; ++nt) {
      colB[nt]  = pCb[cOff + nt * 16];   // SIM_BIAS already folded in prep
      colAd[nt] = pAd[cOff + nt * 16];
    }

    f32x4 c[4][4];
#pragma unroll
    for (int nt = 0; nt < 4; ++nt) {
      const unsigned char* b = pB + (size_t)(cOff + nt * 16) * Dd;
      v8i bf0, bf1;   // kk=0 / kk=1 fragments (contiguous K-bytes, no swizzle)
      i32x4* p0 = reinterpret_cast<i32x4*>(&bf0);
      p0[0] = *reinterpret_cast<const i32x4*>(b);
      p0[1] = *reinterpret_cast<const i32x4*>(b + 16);
      i32x4* p1 = reinterpret_cast<i32x4*>(&bf1);
      p1[0] = *reinterpret_cast<const i32x4*>(b + 128);
      p1[1] = *reinterpret_cast<const i32x4*>(b + 144);
#pragma unroll
      for (int mt = 0; mt < 4; ++mt) {
        const f32x4 t0 = __builtin_amdgcn_mfma_scale_f32_16x16x128_f8f6f4(
            afReg[0][mt], bf0, CZ, 0, 0, 0, SCALE1, 0, SCALE1);
        c[mt][nt] = __builtin_amdgcn_mfma_scale_f32_16x16x128_f8f6f4(
            afReg[1][mt], bf1, t0, 0, 0, 0, SCALE1, 0, SCALE1);
      }
    }

    // ---- epilogue for col-tile ct: exp2-accumulate into registers ----
#pragma unroll
    for (int mt = 0; mt < 4; ++mt) {
#pragma unroll
      for (int r = 0; r < 4; ++r) {
        float a = 0.f, p = 0.f;
#pragma unroll
        for (int nt = 0; nt < 4; ++nt) {
          const float e = __builtin_amdgcn_exp2f(fmaf(c[mt][nt][r], SIM_SCALE, colB[nt]));
          a += e;
          p += (colAd[nt] == rowAd[mt][r]) ? e : 0.f;
        }
        apA[mt][r] += a;
        apP[mt][r] += p;
      }
    }
  }

  // ---- final reduction: shfl-tree over the 16 lq lanes, then one atomic ----
#pragma unroll
  for (int mt = 0; mt < 4; ++mt) {
#pragma unroll
    for (int r = 0; r < 4; ++r) {
      float a = apA[mt][r], p = apP[mt][r];
#pragma unroll
      for (int m = 1; m < 16; m <<= 1) {
        a += __shfl_xor(a, m);
        p += __shfl_xor(p, m);
      }
      if (lq == 0) {
        const int row = rowBase + wrow + mt * 16 + qd * 4 + r;
        atomicAdd(&g_all[row], a);
        atomicAdd(&g_pos[row], p);
      }
    }
  }
}

// ---------------------------------------------------------------------------
// Kernel 3: loss = mean over valid rows of log(g_all) - log(g_pos).
// ---------------------------------------------------------------------------
__global__ __launch_bounds__(1024) void reduce_kernel(const float* __restrict__ g_all,
                                                      const float* __restrict__ g_pos,
                                                      const int* __restrict__ pad,
                                                      float* __restrict__ out) {
  __shared__ float sS[16], sC[16];
  const int t = threadIdx.x;
  float s = 0.f, c = 0.f;
  const float4* ga4 = (const float4*)g_all;
  const float4* gp4 = (const float4*)g_pos;
  const int4*   pd4 = (const int4*)pad;
  for (int i = t; i < Nn / 4; i += 1024) {
    const float4 ga = ga4[i];
    const float4 gp = gp4[i];
    const int4   pd = pd4[i];
    if (pd.x) { s += __logf(ga.x) - __logf(gp.x); c += 1.f; }
    if (pd.y) { s += __logf(ga.y) - __logf(gp.y); c += 1.f; }
    if (pd.z) { s += __logf(ga.z) - __logf(gp.z); c += 1.f; }
    if (pd.w) { s += __logf(ga.w) - __logf(gp.w); c += 1.f; }
  }
#pragma unroll
  for (int m = 32; m >= 1; m >>= 1) {
    s += __shfl_xor(s, m);
    c += __shfl_xor(c, m);
  }
  if ((t & 63) == 0) { sS[t >> 6] = s; sC[t >> 6] = c; }
  __syncthreads();
  if (t == 0) {
    float S = 0.f, C = 0.f;
#pragma unroll
    for (int i = 0; i < 16; ++i) { S += sS[i]; C += sC[i]; }
    out[0] = S / fmaxf(C, 1.0f);
  }
}

extern "C" void kernel_launch(void* const* d_in, const int* in_sizes, int n_in,
                              void* d_out, int out_size, void* d_ws, size_t ws_size,
                              hipStream_t stream) {
  const float* logits = (const float*)d_in[0];
  const float* labels = (const float*)d_in[1];
  const int*   pad    = (const int*)d_in[2];
  const int*   ad     = (const int*)d_in[3];

  char* ws = (char*)d_ws;
  unsigned char* qb = (unsigned char*)(ws);             // 2 MiB (fp8)
  unsigned char* kb = (unsigned char*)(ws + 2097152);   // 2 MiB (fp8)
  float*  cb   = (float*)(ws + 4194304);                // 32 KiB
  float*  gAll = (float*)(ws + 4227072);                // 32 KiB
  float*  gPos = (float*)(ws + 4259840);                // 32 KiB
  float*  out  = (float*)d_out;

  prep_kernel<<<4096, 256, 0, stream>>>(logits, labels, pad, qb, kb, cb, gAll, gPos);
  gemm_lse_kernel<<<dim3(64, 8), 256, 0, stream>>>(qb, kb, cb, ad, gAll, gPos);
  reduce_kernel<<<1, 1024, 0, stream>>>(gAll, gPos, pad, out);
}